// Round 3
// baseline (639.036 us; speedup 1.0000x reference)
//
#include <hip/hip_runtime.h>

constexpr int FIN = 512;
constexpr int HID = 16;
constexpr int NC  = 7;

// ---------------- CSR build ----------------

__global__ void k_hist(const int* __restrict__ dst, int* __restrict__ cnt, int E) {
    int e = blockIdx.x * 256 + threadIdx.x;
    if (e < E) atomicAdd(&cnt[dst[e]], 1);
}

// per-block sums of cnt (256 per block)
__global__ void k_bsum(const int* __restrict__ cnt, int* __restrict__ bsum, int N) {
    int i = blockIdx.x * 256 + threadIdx.x;
    int v = (i < N) ? cnt[i] : 0;
#pragma unroll
    for (int o = 1; o < 64; o <<= 1) v += __shfl_xor(v, o);
    __shared__ int ws_[4];
    if ((threadIdx.x & 63) == 0) ws_[threadIdx.x >> 6] = v;
    __syncthreads();
    if (threadIdx.x == 0) bsum[blockIdx.x] = ws_[0] + ws_[1] + ws_[2] + ws_[3];
}

// single-block exclusive scan of block sums (nb <= 1024)
__global__ void k_scanb(const int* __restrict__ bsum, int* __restrict__ boff, int nb) {
    __shared__ int s[1024];
    int t = threadIdx.x;
    int mine = (t < nb) ? bsum[t] : 0;
    s[t] = mine;
    __syncthreads();
    for (int o = 1; o < 1024; o <<= 1) {
        int v = (t >= o) ? s[t - o] : 0;
        __syncthreads();
        s[t] += v;
        __syncthreads();
    }
    if (t < nb) boff[t] = s[t] - mine;  // exclusive
}

// rowptr = boff[blk] + in-block exclusive scan; cursor = rowptr; dinv = rsqrt(deg+1)
__global__ void k_rowptr(const int* __restrict__ cnt, const int* __restrict__ boff,
                         int* __restrict__ rowptr, int* __restrict__ cursor,
                         float* __restrict__ dinv, int N, int E) {
    int i = blockIdx.x * 256 + threadIdx.x;
    int v = (i < N) ? cnt[i] : 0;
    int lane = threadIdx.x & 63, w = threadIdx.x >> 6;
    int xs = v;
#pragma unroll
    for (int o = 1; o < 64; o <<= 1) {
        int y = __shfl_up(xs, o);
        if (lane >= o) xs += y;
    }
    __shared__ int wsum[4];
    if (lane == 63) wsum[w] = xs;
    __syncthreads();
    int woff = 0;
    for (int k = 0; k < w; ++k) woff += wsum[k];
    if (i < N) {
        int rp = boff[blockIdx.x] + woff + xs - v;
        rowptr[i] = rp;
        cursor[i] = rp;
        dinv[i] = rsqrtf((float)v + 1.0f);
    }
    if (i == N) rowptr[N] = E;
}

__global__ void k_fill(const int* __restrict__ src, const int* __restrict__ dst,
                       int* __restrict__ cursor, int* __restrict__ esrc, int E) {
    int e = blockIdx.x * 256 + threadIdx.x;
    if (e < E) {
        int p = atomicAdd(&cursor[dst[e]], 1);
        esrc[p] = src[e];
    }
}

// ---------------- layer 0 transform: acc0 += x @ W0 (k-split x4, LDS dbuf) --------

constexpr int SPLIT = 4;
constexpr int KR = FIN / SPLIT;  // 128 k per block
constexpr int KC = 16;           // chunk
constexpr int NCH = KR / KC;     // 8 chunks

__global__ void __launch_bounds__(256) k_xw0(
    const float* __restrict__ x, const float* __restrict__ W0,
    float* __restrict__ acc0, int N) {
    __shared__ float xl[2][256][KC + 1];  // 2 x 17 KB, stride 17 -> 2-way (free)

    const int rb = blockIdx.x / SPLIT;
    const int ks = blockIdx.x % SPLIT;
    const int row0 = rb * 256;
    const int kb = ks * KR;
    const int tid = threadIdx.x;
    const int q = tid & 3;        // float4 slot within 16-float chunk
    const int rbase = tid >> 2;   // 0..63

    float4 ld[4];
    // prologue: chunk 0 -> regs -> buf0
#pragma unroll
    for (int i = 0; i < 4; ++i) {
        int grow = row0 + i * 64 + rbase;
        if (grow >= N) grow = N - 1;
        ld[i] = *(const float4*)(x + (size_t)grow * FIN + kb + q * 4);
    }
#pragma unroll
    for (int i = 0; i < 4; ++i) {
        int r = i * 64 + rbase;
        xl[0][r][q * 4 + 0] = ld[i].x;
        xl[0][r][q * 4 + 1] = ld[i].y;
        xl[0][r][q * 4 + 2] = ld[i].z;
        xl[0][r][q * 4 + 3] = ld[i].w;
    }

    float acc[HID];
#pragma unroll
    for (int j = 0; j < HID; ++j) acc[j] = 0.f;

    for (int ch = 0; ch < NCH; ++ch) {
        int cur = ch & 1;
        __syncthreads();  // buf[cur] ready
        // issue next chunk's loads; they drain at the post-compute barrier
        if (ch + 1 < NCH) {
            int kc = (ch + 1) * KC;
#pragma unroll
            for (int i = 0; i < 4; ++i) {
                int grow = row0 + i * 64 + rbase;
                if (grow >= N) grow = N - 1;
                ld[i] = *(const float4*)(x + (size_t)grow * FIN + kb + kc + q * 4);
            }
        }
        const float* wk = W0 + (size_t)(kb + ch * KC) * HID;  // uniform -> s_load
#pragma unroll
        for (int kk = 0; kk < KC; ++kk) {
            float xv = xl[cur][tid][kk];
#pragma unroll
            for (int j = 0; j < HID; ++j)
                acc[j] = fmaf(xv, wk[kk * HID + j], acc[j]);
        }
        __syncthreads();  // reads of buf[cur^1] (prev iter) done; loads drained
        if (ch + 1 < NCH) {
#pragma unroll
            for (int i = 0; i < 4; ++i) {
                int r = i * 64 + rbase;
                int nb_ = cur ^ 1;
                xl[nb_][r][q * 4 + 0] = ld[i].x;
                xl[nb_][r][q * 4 + 1] = ld[i].y;
                xl[nb_][r][q * 4 + 2] = ld[i].z;
                xl[nb_][r][q * 4 + 3] = ld[i].w;
            }
        }
    }

    int row = row0 + tid;
    if (row < N) {
#pragma unroll
        for (int j = 0; j < HID; ++j)
            atomicAdd(&acc0[(size_t)row * HID + j], acc[j]);
    }
}

// g0 = acc0 * dinv (in-place, float4)
__global__ void k_g0(float4* __restrict__ g, const float* __restrict__ dinv, int n4) {
    int t = blockIdx.x * 256 + threadIdx.x;
    if (t >= n4) return;
    float dv = dinv[t >> 2];
    float4 v = g[t];
    v.x *= dv; v.y *= dv; v.z *= dv; v.w *= dv;
    g[t] = v;
}

// ---------------- pull aggregation (no atomics) ----------------

// s0[d][j] = g0[d][j] + sum_{e in row d} g0[esrc[e]][j]
__global__ void k_pull0(const int* __restrict__ rowptr, const int* __restrict__ esrc,
                        const float* __restrict__ g0, float* __restrict__ s0, int N) {
    int t = blockIdx.x * 256 + threadIdx.x;
    int d = t >> 4;
    if (d >= N) return;
    int j = t & 15;
    int e0 = rowptr[d], e1 = rowptr[d + 1];
    float acc = g0[(size_t)d * HID + j];  // self loop
    int e = e0;
    for (; e + 1 < e1; e += 2) {  // 2-way unroll for MLP
        int a = esrc[e], b = esrc[e + 1];
        float va = g0[(size_t)a * HID + j];
        float vb = g0[(size_t)b * HID + j];
        acc += va;
        acc += vb;
    }
    if (e < e1) acc += g0[(size_t)esrc[e] * HID + j];
    s0[(size_t)d * HID + j] = acc;
}

// h1 = relu(s0*dinv + b0); g1 = (h1 @ W1) * dinv
__global__ void k_h1w1(const float* __restrict__ s0, const float* __restrict__ dinv,
                       const float* __restrict__ b0, const float* __restrict__ W1,
                       float* __restrict__ g1, int N) {
    int i = blockIdx.x * 256 + threadIdx.x;
    if (i >= N) return;
    float dv = dinv[i];
    const float4* sp = (const float4*)(s0 + (size_t)i * HID);
    float4 a = sp[0], b = sp[1], c = sp[2], d = sp[3];
    float h[HID] = {a.x, a.y, a.z, a.w, b.x, b.y, b.z, b.w,
                    c.x, c.y, c.z, c.w, d.x, d.y, d.z, d.w};
#pragma unroll
    for (int j = 0; j < HID; ++j) h[j] = fmaxf(fmaf(h[j], dv, b0[j]), 0.f);
    float o[NC];
#pragma unroll
    for (int c2 = 0; c2 < NC; ++c2) o[c2] = 0.f;
#pragma unroll
    for (int j = 0; j < HID; ++j)
#pragma unroll
        for (int c2 = 0; c2 < NC; ++c2)
            o[c2] = fmaf(h[j], W1[j * NC + c2], o[c2]);  // uniform -> s_load
#pragma unroll
    for (int c2 = 0; c2 < NC; ++c2)
        g1[(size_t)i * NC + c2] = o[c2] * dv;
}

// out[d][c] = (g1[d][c] + sum g1[src][c]) * dinv[d] + b1[c]
__global__ void k_pull1(const int* __restrict__ rowptr, const int* __restrict__ esrc,
                        const float* __restrict__ g1, const float* __restrict__ dinv,
                        const float* __restrict__ b1, float* __restrict__ outp, int N) {
    int t = blockIdx.x * 256 + threadIdx.x;
    int d = t >> 3;
    if (d >= N) return;
    int c = t & 7;
    if (c >= NC) return;
    int e0 = rowptr[d], e1 = rowptr[d + 1];
    float acc = g1[(size_t)d * NC + c];  // self loop
    int e = e0;
    for (; e + 1 < e1; e += 2) {
        int a = esrc[e], b = esrc[e + 1];
        float va = g1[(size_t)a * NC + c];
        float vb = g1[(size_t)b * NC + c];
        acc += va;
        acc += vb;
    }
    if (e < e1) acc += g1[(size_t)esrc[e] * NC + c];
    outp[(size_t)d * NC + c] = fmaf(acc, dinv[d], b1[c]);
}

// ---------------- launch ----------------

extern "C" void kernel_launch(void* const* d_in, const int* in_sizes, int n_in,
                              void* d_out, int out_size, void* d_ws, size_t ws_size,
                              hipStream_t stream) {
    const float* x  = (const float*)d_in[0];
    const int*   ei = (const int*)d_in[1];
    const float* W0 = (const float*)d_in[2];
    const float* b0 = (const float*)d_in[3];
    const float* W1 = (const float*)d_in[4];
    const float* b1 = (const float*)d_in[5];
    float* outp = (float*)d_out;

    int N = in_sizes[0] / FIN;
    int E = in_sizes[1] / 2;
    const int* src = ei;
    const int* dst = ei + E;

    // ws layout: floats [ g0:16N | s0:16N | g1:7N | dinv:N ] then ints
    float* fws = (float*)d_ws;
    float* g0   = fws;                       // doubles as acc0
    float* s0   = fws + (size_t)16 * N;
    float* g1   = fws + (size_t)32 * N;
    float* dinv = fws + (size_t)39 * N;
    int* iws    = (int*)(fws + (size_t)40 * N);
    int* rowptr = iws;                       // N+1
    int* cursor = iws + (N + 1);             // N
    int* cnt    = iws + (2 * N + 1);         // N
    int* bsum   = iws + (3 * N + 1);         // 1024
    int* boff   = iws + (3 * N + 1 + 1024);  // 1024
    int* esrc   = iws + (3 * N + 1 + 2048);  // E

    int nb = (N + 255) / 256;

    hipMemsetAsync(cnt, 0, (size_t)N * sizeof(int), stream);
    hipMemsetAsync(g0, 0, (size_t)16 * N * sizeof(float), stream);

    k_hist<<<(E + 255) / 256, 256, 0, stream>>>(dst, cnt, E);
    k_bsum<<<nb, 256, 0, stream>>>(cnt, bsum, N);
    k_scanb<<<1, 1024, 0, stream>>>(bsum, boff, nb);
    k_rowptr<<<(N + 1 + 255) / 256, 256, 0, stream>>>(cnt, boff, rowptr, cursor, dinv, N, E);
    k_fill<<<(E + 255) / 256, 256, 0, stream>>>(src, dst, cursor, esrc, E);

    k_xw0<<<nb * SPLIT, 256, 0, stream>>>(x, W0, g0, N);
    k_g0<<<(4 * N + 255) / 256, 256, 0, stream>>>((float4*)g0, dinv, 4 * N);
    k_pull0<<<(int)(((size_t)N * 16 + 255) / 256), 256, 0, stream>>>(rowptr, esrc, g0, s0, N);
    k_h1w1<<<nb, 256, 0, stream>>>(s0, dinv, b0, W1, g1, N);
    k_pull1<<<(int)(((size_t)N * 8 + 255) / 256), 256, 0, stream>>>(rowptr, esrc, g1, dinv, b1, outp, N);
}

// Round 4
// 374.915 us; speedup vs baseline: 1.7045x; 1.7045x over previous
//
#include <hip/hip_runtime.h>

constexpr int FIN = 512;
constexpr int HID = 16;
constexpr int NC  = 7;

// ---------------- CSR build ----------------

__global__ void k_hist(const int* __restrict__ dst, int* __restrict__ cnt, int E) {
    int e = blockIdx.x * 256 + threadIdx.x;
    if (e < E) atomicAdd(&cnt[dst[e]], 1);
}

// per-block sums of cnt (256 per block)
__global__ void k_bsum(const int* __restrict__ cnt, int* __restrict__ bsum, int N) {
    int i = blockIdx.x * 256 + threadIdx.x;
    int v = (i < N) ? cnt[i] : 0;
#pragma unroll
    for (int o = 1; o < 64; o <<= 1) v += __shfl_xor(v, o);
    __shared__ int ws_[4];
    if ((threadIdx.x & 63) == 0) ws_[threadIdx.x >> 6] = v;
    __syncthreads();
    if (threadIdx.x == 0) bsum[blockIdx.x] = ws_[0] + ws_[1] + ws_[2] + ws_[3];
}

// single-block exclusive scan of block sums (nb <= 1024)
__global__ void k_scanb(const int* __restrict__ bsum, int* __restrict__ boff, int nb) {
    __shared__ int s[1024];
    int t = threadIdx.x;
    int mine = (t < nb) ? bsum[t] : 0;
    s[t] = mine;
    __syncthreads();
    for (int o = 1; o < 1024; o <<= 1) {
        int v = (t >= o) ? s[t - o] : 0;
        __syncthreads();
        s[t] += v;
        __syncthreads();
    }
    if (t < nb) boff[t] = s[t] - mine;  // exclusive
}

// rowptr = boff[blk] + in-block exclusive scan; cursor = rowptr; dinv = rsqrt(deg+1)
__global__ void k_rowptr(const int* __restrict__ cnt, const int* __restrict__ boff,
                         int* __restrict__ rowptr, int* __restrict__ cursor,
                         float* __restrict__ dinv, int N, int E) {
    int i = blockIdx.x * 256 + threadIdx.x;
    int v = (i < N) ? cnt[i] : 0;
    int lane = threadIdx.x & 63, w = threadIdx.x >> 6;
    int xs = v;
#pragma unroll
    for (int o = 1; o < 64; o <<= 1) {
        int y = __shfl_up(xs, o);
        if (lane >= o) xs += y;
    }
    __shared__ int wsum[4];
    if (lane == 63) wsum[w] = xs;
    __syncthreads();
    int woff = 0;
    for (int k = 0; k < w; ++k) woff += wsum[k];
    if (i < N) {
        int rp = boff[blockIdx.x] + woff + xs - v;
        rowptr[i] = rp;
        cursor[i] = rp;
        dinv[i] = rsqrtf((float)v + 1.0f);
    }
    if (i == N) rowptr[N] = E;
}

__global__ void k_fill(const int* __restrict__ src, const int* __restrict__ dst,
                       int* __restrict__ cursor, int* __restrict__ esrc, int E) {
    int e = blockIdx.x * 256 + threadIdx.x;
    if (e < E) {
        int p = atomicAdd(&cursor[dst[e]], 1);
        esrc[p] = src[e];
    }
}

// ---------------- layer 0 transform: g0 = (x @ W0) * dinv ----------------
// Thread-per-row, register double-buffered streaming (no LDS, no barriers,
// no atomics). W0 accessed at wave-uniform addresses -> s_load broadcast.

__global__ void __launch_bounds__(256) k_xw0(
    const float* __restrict__ x, const float* __restrict__ W0,
    const float* __restrict__ dinv, float* __restrict__ g0, int N) {
    int row = blockIdx.x * 256 + threadIdx.x;
    int r = row < N ? row : N - 1;
    const float4* xr = (const float4*)(x + (size_t)r * FIN);

    float acc[HID];
#pragma unroll
    for (int j = 0; j < HID; ++j) acc[j] = 0.f;

    float4 A[16], B[16];
#pragma unroll
    for (int i = 0; i < 16; ++i) A[i] = xr[i];  // batch 0 in flight

#pragma unroll
    for (int b = 0; b < 8; ++b) {           // 8 batches x 64 floats
        const float4* cur = (b & 1) ? B : A;
        float4* nxt = (b & 1) ? A : B;
        if (b + 1 < 8) {
#pragma unroll
            for (int i = 0; i < 16; ++i) nxt[i] = xr[(b + 1) * 16 + i];
        }
        const float* wb = W0 + (size_t)b * 64 * HID;  // wave-uniform -> s_load
#pragma unroll
        for (int i = 0; i < 16; ++i) {
            const float* w = wb + i * 4 * HID;
            float4 xv = cur[i];
#pragma unroll
            for (int j = 0; j < HID; ++j) {
                acc[j] = fmaf(xv.x, w[j], acc[j]);
                acc[j] = fmaf(xv.y, w[HID + j], acc[j]);
                acc[j] = fmaf(xv.z, w[2 * HID + j], acc[j]);
                acc[j] = fmaf(xv.w, w[3 * HID + j], acc[j]);
            }
        }
    }

    if (row < N) {
        float dv = dinv[row];
        float4* gp = (float4*)(g0 + (size_t)row * HID);
#pragma unroll
        for (int q = 0; q < 4; ++q) {
            float4 v;
            v.x = acc[q * 4 + 0] * dv;
            v.y = acc[q * 4 + 1] * dv;
            v.z = acc[q * 4 + 2] * dv;
            v.w = acc[q * 4 + 3] * dv;
            gp[q] = v;
        }
    }
}

// ---------------- pull aggregation (wave per dst row) ----------------

// s0[d][j] = g0[d][j] + sum_{e in row d} g0[esrc[e]][j]
// 64 lanes = 4 edge-slots x 16 features.
__global__ void k_pull0(const int* __restrict__ rowptr, const int* __restrict__ esrc,
                        const float* __restrict__ g0, float* __restrict__ s0, int N) {
    int wid = (blockIdx.x * 256 + threadIdx.x) >> 6;
    if (wid >= N) return;
    int lane = threadIdx.x & 63;
    int slot = lane >> 4, j = lane & 15;
    int e0 = rowptr[wid], e1 = rowptr[wid + 1];  // uniform -> s_load
    float acc = 0.f;
    for (int e = e0 + slot; e < e1; e += 4) {
        int a = esrc[e];
        acc += g0[(size_t)a * HID + j];
    }
    acc += __shfl_xor(acc, 16);
    acc += __shfl_xor(acc, 32);
    if (slot == 0)
        s0[(size_t)wid * HID + j] = acc + g0[(size_t)wid * HID + j];
}

// h1 = relu(s0*dinv + b0); g1 = (h1 @ W1) * dinv
__global__ void k_h1w1(const float* __restrict__ s0, const float* __restrict__ dinv,
                       const float* __restrict__ b0, const float* __restrict__ W1,
                       float* __restrict__ g1, int N) {
    int i = blockIdx.x * 256 + threadIdx.x;
    if (i >= N) return;
    float dv = dinv[i];
    const float4* sp = (const float4*)(s0 + (size_t)i * HID);
    float4 a = sp[0], b = sp[1], c = sp[2], d = sp[3];
    float h[HID] = {a.x, a.y, a.z, a.w, b.x, b.y, b.z, b.w,
                    c.x, c.y, c.z, c.w, d.x, d.y, d.z, d.w};
#pragma unroll
    for (int j = 0; j < HID; ++j) h[j] = fmaxf(fmaf(h[j], dv, b0[j]), 0.f);
    float o[NC];
#pragma unroll
    for (int c2 = 0; c2 < NC; ++c2) o[c2] = 0.f;
#pragma unroll
    for (int j = 0; j < HID; ++j)
#pragma unroll
        for (int c2 = 0; c2 < NC; ++c2)
            o[c2] = fmaf(h[j], W1[j * NC + c2], o[c2]);  // uniform -> s_load
#pragma unroll
    for (int c2 = 0; c2 < NC; ++c2)
        g1[(size_t)i * NC + c2] = o[c2] * dv;
}

// out[d][c] = (g1[d][c] + sum g1[src][c]) * dinv[d] + b1[c]
// 64 lanes = 8 edge-slots x 8 feature-slots (7 used).
__global__ void k_pull1(const int* __restrict__ rowptr, const int* __restrict__ esrc,
                        const float* __restrict__ g1, const float* __restrict__ dinv,
                        const float* __restrict__ b1, float* __restrict__ outp, int N) {
    int wid = (blockIdx.x * 256 + threadIdx.x) >> 6;
    if (wid >= N) return;
    int lane = threadIdx.x & 63;
    int slot = lane >> 3, j = lane & 7;
    int e0 = rowptr[wid], e1 = rowptr[wid + 1];  // uniform -> s_load
    float acc = 0.f;
    for (int e = e0 + slot; e < e1; e += 8) {
        int a = esrc[e];
        if (j < NC) acc += g1[(size_t)a * NC + j];
    }
    acc += __shfl_xor(acc, 8);
    acc += __shfl_xor(acc, 16);
    acc += __shfl_xor(acc, 32);
    if (slot == 0 && j < NC)
        outp[(size_t)wid * NC + j] =
            fmaf(acc + g1[(size_t)wid * NC + j], dinv[wid], b1[j]);
}

// ---------------- launch ----------------

extern "C" void kernel_launch(void* const* d_in, const int* in_sizes, int n_in,
                              void* d_out, int out_size, void* d_ws, size_t ws_size,
                              hipStream_t stream) {
    const float* x  = (const float*)d_in[0];
    const int*   ei = (const int*)d_in[1];
    const float* W0 = (const float*)d_in[2];
    const float* b0 = (const float*)d_in[3];
    const float* W1 = (const float*)d_in[4];
    const float* b1 = (const float*)d_in[5];
    float* outp = (float*)d_out;

    int N = in_sizes[0] / FIN;
    int E = in_sizes[1] / 2;
    const int* src = ei;
    const int* dst = ei + E;

    // ws layout: floats [ g0:16N | s0:16N | g1:7N | dinv:N ] then ints
    float* fws = (float*)d_ws;
    float* g0   = fws;
    float* s0   = fws + (size_t)16 * N;
    float* g1   = fws + (size_t)32 * N;
    float* dinv = fws + (size_t)39 * N;
    int* iws    = (int*)(fws + (size_t)40 * N);
    int* rowptr = iws;                       // N+1
    int* cursor = iws + (N + 1);             // N
    int* cnt    = iws + (2 * N + 1);         // N
    int* bsum   = iws + (3 * N + 1);         // 1024
    int* boff   = iws + (3 * N + 1 + 1024);  // 1024
    int* esrc   = iws + (3 * N + 1 + 2048);  // E

    int nb = (N + 255) / 256;

    hipMemsetAsync(cnt, 0, (size_t)N * sizeof(int), stream);

    k_hist<<<(E + 255) / 256, 256, 0, stream>>>(dst, cnt, E);
    k_bsum<<<nb, 256, 0, stream>>>(cnt, bsum, N);
    k_scanb<<<1, 1024, 0, stream>>>(bsum, boff, nb);
    k_rowptr<<<(N + 1 + 255) / 256, 256, 0, stream>>>(cnt, boff, rowptr, cursor, dinv, N, E);
    k_fill<<<(E + 255) / 256, 256, 0, stream>>>(src, dst, cursor, esrc, E);

    k_xw0<<<nb, 256, 0, stream>>>(x, W0, dinv, g0, N);
    k_pull0<<<(int)(((size_t)N * 64 + 255) / 256), 256, 0, stream>>>(rowptr, esrc, g0, s0, N);
    k_h1w1<<<nb, 256, 0, stream>>>(s0, dinv, b0, W1, g1, N);
    k_pull1<<<(int)(((size_t)N * 64 + 255) / 256), 256, 0, stream>>>(rowptr, esrc, g1, dinv, b1, outp, N);
}

// Round 5
// 259.911 us; speedup vs baseline: 2.4587x; 1.4425x over previous
//
#include <hip/hip_runtime.h>

constexpr int FIN = 512;
constexpr int HID = 16;
constexpr int NC  = 7;

// ---------------- CSR build ----------------

__global__ void k_hist(const int* __restrict__ dst, int* __restrict__ cnt, int E) {
    int e = blockIdx.x * 256 + threadIdx.x;
    if (e < E) atomicAdd(&cnt[dst[e]], 1);
}

// per-block sums of cnt (256 per block)
__global__ void k_bsum(const int* __restrict__ cnt, int* __restrict__ bsum, int N) {
    int i = blockIdx.x * 256 + threadIdx.x;
    int v = (i < N) ? cnt[i] : 0;
#pragma unroll
    for (int o = 1; o < 64; o <<= 1) v += __shfl_xor(v, o);
    __shared__ int ws_[4];
    if ((threadIdx.x & 63) == 0) ws_[threadIdx.x >> 6] = v;
    __syncthreads();
    if (threadIdx.x == 0) bsum[blockIdx.x] = ws_[0] + ws_[1] + ws_[2] + ws_[3];
}

// single-block exclusive scan of block sums (nb <= 1024)
__global__ void k_scanb(const int* __restrict__ bsum, int* __restrict__ boff, int nb) {
    __shared__ int s[1024];
    int t = threadIdx.x;
    int mine = (t < nb) ? bsum[t] : 0;
    s[t] = mine;
    __syncthreads();
    for (int o = 1; o < 1024; o <<= 1) {
        int v = (t >= o) ? s[t - o] : 0;
        __syncthreads();
        s[t] += v;
        __syncthreads();
    }
    if (t < nb) boff[t] = s[t] - mine;  // exclusive
}

// rowptr = boff[blk] + in-block exclusive scan; cursor = rowptr; dinv = rsqrt(deg+1)
__global__ void k_rowptr(const int* __restrict__ cnt, const int* __restrict__ boff,
                         int* __restrict__ rowptr, int* __restrict__ cursor,
                         float* __restrict__ dinv, int N, int E) {
    int i = blockIdx.x * 256 + threadIdx.x;
    int v = (i < N) ? cnt[i] : 0;
    int lane = threadIdx.x & 63, w = threadIdx.x >> 6;
    int xs = v;
#pragma unroll
    for (int o = 1; o < 64; o <<= 1) {
        int y = __shfl_up(xs, o);
        if (lane >= o) xs += y;
    }
    __shared__ int wsum[4];
    if (lane == 63) wsum[w] = xs;
    __syncthreads();
    int woff = 0;
    for (int k = 0; k < w; ++k) woff += wsum[k];
    if (i < N) {
        int rp = boff[blockIdx.x] + woff + xs - v;
        rowptr[i] = rp;
        cursor[i] = rp;
        dinv[i] = rsqrtf((float)v + 1.0f);
    }
    if (i == N) rowptr[N] = E;
}

// ---------------- fused: g0 = (x @ W0) * dinv  (+ CSR fill) ----------------
// xw0 blocks: 64 threads, thread-per-row, register ping-pong with
// sched_barrier fences so 16 float4 loads stay in flight under each FMA batch.
// fill blocks: scatter esrc via cursor atomics (hides under xw0's BW phase).

__global__ void __launch_bounds__(64) k_xw0_fill(
    const float* __restrict__ x, const float* __restrict__ W0,
    const float* __restrict__ dinv, float* __restrict__ g0, int N, int nbx,
    const int* __restrict__ src, const int* __restrict__ dst,
    int* __restrict__ cursor, int* __restrict__ esrc, int E) {
    if ((int)blockIdx.x >= nbx) {
        int e = (blockIdx.x - nbx) * 64 + threadIdx.x;
        if (e < E) {
            int p = atomicAdd(&cursor[dst[e]], 1);
            esrc[p] = src[e];
        }
        return;
    }

    int row = blockIdx.x * 64 + threadIdx.x;
    int r = row < N ? row : N - 1;
    const float4* xr = (const float4*)(x + (size_t)r * FIN);

    float acc[HID];
#pragma unroll
    for (int j = 0; j < HID; ++j) acc[j] = 0.f;

    float4 A[16], B[16];
#pragma unroll
    for (int i = 0; i < 16; ++i) A[i] = xr[i];  // batch 0 in flight
    __builtin_amdgcn_sched_barrier(0);

#pragma unroll
    for (int b = 0; b < 8; ++b) {  // 8 batches x 64 floats
        const float4* cur = (b & 1) ? B : A;
        float4* nxt = (b & 1) ? A : B;
        if (b + 1 < 8) {
#pragma unroll
            for (int i = 0; i < 16; ++i) nxt[i] = xr[(b + 1) * 16 + i];
        }
        __builtin_amdgcn_sched_barrier(0);  // loads above stay above
        const float* wb = W0 + (size_t)b * 64 * HID;  // wave-uniform -> s_load
#pragma unroll
        for (int i = 0; i < 16; ++i) {
            const float* w = wb + i * 4 * HID;
            float4 xv = cur[i];
#pragma unroll
            for (int j = 0; j < HID; ++j) {
                acc[j] = fmaf(xv.x, w[j], acc[j]);
                acc[j] = fmaf(xv.y, w[HID + j], acc[j]);
                acc[j] = fmaf(xv.z, w[2 * HID + j], acc[j]);
                acc[j] = fmaf(xv.w, w[3 * HID + j], acc[j]);
            }
        }
        __builtin_amdgcn_sched_barrier(0);  // compute stays before next issue
    }

    if (row < N) {
        float dv = dinv[row];
        float4* gp = (float4*)(g0 + (size_t)row * HID);
#pragma unroll
        for (int q = 0; q < 4; ++q) {
            float4 v;
            v.x = acc[q * 4 + 0] * dv;
            v.y = acc[q * 4 + 1] * dv;
            v.z = acc[q * 4 + 2] * dv;
            v.w = acc[q * 4 + 3] * dv;
            gp[q] = v;
        }
    }
}

// ---------------- pull aggregation (wave per dst row, batched gathers) -------

// s0[d][j] = g0[d][j] + sum_{e in row d} g0[esrc[e]][j]
// 16 indices loaded coalesced, shfl-broadcast, 4 independent gathers per lane.
__global__ void k_pull0(const int* __restrict__ rowptr, const int* __restrict__ esrc,
                        const float* __restrict__ g0, float* __restrict__ s0, int N) {
    int wid = (blockIdx.x * 256 + threadIdx.x) >> 6;
    if (wid >= N) return;
    int lane = threadIdx.x & 63;
    int grp = lane >> 4, j = lane & 15;
    int e0 = rowptr[wid], e1 = rowptr[wid + 1];
    float acc = 0.f;
    for (int base = e0; base < e1; base += 16) {
        int p = base + (lane & 15);
        int v = (p < e1) ? esrc[p] : 0;
#pragma unroll
        for (int u = 0; u < 4; ++u) {
            int k = grp + 4 * u;
            int idx = __shfl(v, k);
            if (base + k < e1) acc += g0[(size_t)idx * HID + j];
        }
    }
    acc += __shfl_xor(acc, 16);
    acc += __shfl_xor(acc, 32);
    if (grp == 0)
        s0[(size_t)wid * HID + j] = acc + g0[(size_t)wid * HID + j];
}

// h1 = relu(s0*dinv + b0); g1 = (h1 @ W1) * dinv
__global__ void k_h1w1(const float* __restrict__ s0, const float* __restrict__ dinv,
                       const float* __restrict__ b0, const float* __restrict__ W1,
                       float* __restrict__ g1, int N) {
    int i = blockIdx.x * 256 + threadIdx.x;
    if (i >= N) return;
    float dv = dinv[i];
    const float4* sp = (const float4*)(s0 + (size_t)i * HID);
    float4 a = sp[0], b = sp[1], c = sp[2], d = sp[3];
    float h[HID] = {a.x, a.y, a.z, a.w, b.x, b.y, b.z, b.w,
                    c.x, c.y, c.z, c.w, d.x, d.y, d.z, d.w};
#pragma unroll
    for (int j = 0; j < HID; ++j) h[j] = fmaxf(fmaf(h[j], dv, b0[j]), 0.f);
    float o[NC];
#pragma unroll
    for (int c2 = 0; c2 < NC; ++c2) o[c2] = 0.f;
#pragma unroll
    for (int j = 0; j < HID; ++j)
#pragma unroll
        for (int c2 = 0; c2 < NC; ++c2)
            o[c2] = fmaf(h[j], W1[j * NC + c2], o[c2]);  // uniform -> s_load
#pragma unroll
    for (int c2 = 0; c2 < NC; ++c2)
        g1[(size_t)i * NC + c2] = o[c2] * dv;
}

// out[d][c] = (g1[d][c] + sum g1[src][c]) * dinv[d] + b1[c]
// 8 grps x 8 j-slots; 16 indices per superiteration, 2 gathers per lane.
__global__ void k_pull1(const int* __restrict__ rowptr, const int* __restrict__ esrc,
                        const float* __restrict__ g1, const float* __restrict__ dinv,
                        const float* __restrict__ b1, float* __restrict__ outp, int N) {
    int wid = (blockIdx.x * 256 + threadIdx.x) >> 6;
    if (wid >= N) return;
    int lane = threadIdx.x & 63;
    int grp = lane >> 3, j = lane & 7;
    int e0 = rowptr[wid], e1 = rowptr[wid + 1];
    float acc = 0.f;
    for (int base = e0; base < e1; base += 16) {
        int p = base + (lane & 15);
        int v = (p < e1) ? esrc[p] : 0;
#pragma unroll
        for (int u = 0; u < 2; ++u) {
            int k = grp + 8 * u;
            int idx = __shfl(v, k);
            if (base + k < e1 && j < NC) acc += g1[(size_t)idx * NC + j];
        }
    }
    acc += __shfl_xor(acc, 8);
    acc += __shfl_xor(acc, 16);
    acc += __shfl_xor(acc, 32);
    if (grp == 0 && j < NC)
        outp[(size_t)wid * NC + j] =
            fmaf(acc + g1[(size_t)wid * NC + j], dinv[wid], b1[j]);
}

// ---------------- launch ----------------

extern "C" void kernel_launch(void* const* d_in, const int* in_sizes, int n_in,
                              void* d_out, int out_size, void* d_ws, size_t ws_size,
                              hipStream_t stream) {
    const float* x  = (const float*)d_in[0];
    const int*   ei = (const int*)d_in[1];
    const float* W0 = (const float*)d_in[2];
    const float* b0 = (const float*)d_in[3];
    const float* W1 = (const float*)d_in[4];
    const float* b1 = (const float*)d_in[5];
    float* outp = (float*)d_out;

    int N = in_sizes[0] / FIN;
    int E = in_sizes[1] / 2;
    const int* src = ei;
    const int* dst = ei + E;

    // ws layout: floats [ g0:16N | s0:16N | g1:7N | dinv:N ] then ints
    float* fws = (float*)d_ws;
    float* g0   = fws;
    float* s0   = fws + (size_t)16 * N;
    float* g1   = fws + (size_t)32 * N;
    float* dinv = fws + (size_t)39 * N;
    int* iws    = (int*)(fws + (size_t)40 * N);
    int* rowptr = iws;                       // N+1
    int* cursor = iws + (N + 1);             // N
    int* cnt    = iws + (2 * N + 1);         // N
    int* bsum   = iws + (3 * N + 1);         // 1024
    int* boff   = iws + (3 * N + 1 + 1024);  // 1024
    int* esrc   = iws + (3 * N + 1 + 2048);  // E

    int nb = (N + 255) / 256;
    int nbx = (N + 63) / 64;
    int nbf = (E + 63) / 64;

    hipMemsetAsync(cnt, 0, (size_t)N * sizeof(int), stream);

    k_hist<<<(E + 255) / 256, 256, 0, stream>>>(dst, cnt, E);
    k_bsum<<<nb, 256, 0, stream>>>(cnt, bsum, N);
    k_scanb<<<1, 1024, 0, stream>>>(bsum, boff, nb);
    k_rowptr<<<(N + 1 + 255) / 256, 256, 0, stream>>>(cnt, boff, rowptr, cursor, dinv, N, E);

    k_xw0_fill<<<nbx + nbf, 64, 0, stream>>>(x, W0, dinv, g0, N, nbx,
                                             src, dst, cursor, esrc, E);

    k_pull0<<<(int)(((size_t)N * 64 + 255) / 256), 256, 0, stream>>>(rowptr, esrc, g0, s0, N);
    k_h1w1<<<nb, 256, 0, stream>>>(s0, dinv, b0, W1, g1, N);
    k_pull1<<<(int)(((size_t)N * 64 + 255) / 256), 256, 0, stream>>>(rowptr, esrc, g1, dinv, b1, outp, N);
}